// Round 15
// baseline (76.000 us; speedup 1.0000x reference)
//
#include <hip/hip_runtime.h>
#include <hip/hip_bf16.h>

// Problem constants: B=8, C=64, C8=8, H=128, W=128
#define BDIM 8
#define CDIM 64
#define C8DIM 8
#define HDIM 128
#define WDIM 128
#define HW (HDIM * WDIM)   // 16384

typedef short bf16x8 __attribute__((ext_vector_type(8)));
typedef float f32x4 __attribute__((ext_vector_type(4)));

// ---------------- bf16 helpers ----------------
__device__ inline unsigned pk_bf16(float a, float b) {
    unsigned ua = (unsigned)__bfloat16_as_ushort(__float2bfloat16(a));
    unsigned ub = (unsigned)__bfloat16_as_ushort(__float2bfloat16(b));
    return ua | (ub << 16);
}
__device__ inline void cvt2(unsigned u, float& lo, float& hi) {
    lo = __uint_as_float(u << 16);
    hi = __uint_as_float(u & 0xffff0000u);
}

// ---------------------------------------------------------------------------
// Kernel 0 (prep): pack unified weight Wall[80][128] to bf16 (linear) + bias.
// Row o: o<8 -> Wq (cols 0..63), o<16 -> Wk (cols 64..127), else Wv.
// One block, 512 threads, ~10 iters. Runs once, ~2 us.
// ---------------------------------------------------------------------------
__global__ __launch_bounds__(512) void prep_kernel(
    const float* __restrict__ Wq, const float* __restrict__ bq,
    const float* __restrict__ Wk, const float* __restrict__ bk,
    const float* __restrict__ Wv, const float* __restrict__ bv,
    unsigned* __restrict__ wpack, float* __restrict__ wbias)
{
    const int t = threadIdx.x;
    for (int i = t; i < 80 * 64; i += 512) {
        int o = i >> 6;
        int c = (i & 63) * 2;
        float w0, w1;
        if (o < 8) {
            if (c < 64) { w0 = Wq[o * 64 + c]; w1 = Wq[o * 64 + c + 1]; }
            else        { w0 = 0.f; w1 = 0.f; }
        } else if (o < 16) {
            if (c >= 64) { w0 = Wk[(o - 8) * 64 + c - 64]; w1 = Wk[(o - 8) * 64 + c - 63]; }
            else         { w0 = 0.f; w1 = 0.f; }
        } else {
            w0 = Wv[(o - 16) * 128 + c];
            w1 = Wv[(o - 16) * 128 + c + 1];
        }
        wpack[i] = pk_bf16(w0, w1);
    }
    if (t < 80) {
        wbias[t] = (t < 8) ? bq[t] : (t < 16) ? bk[t - 8] : bv[t - 16];
    }
}

// ---------------------------------------------------------------------------
// Kernel 1: fused QKV projection as MFMA GEMM -- NO LDS, NO BARRIERS.
// 2048 blocks x 256 threads (4 waves); block = (b, 64-position tile); wave
// owns 16 positions. A-fragments stream from the 20KB packed weight image
// (global_load_dwordx4, L2-broadcast); B-fragments are per-lane scalar x/y
// loads (round-10-proven path). Compiler interleaves all loads freely --
// no vmcnt(0)-draining barrier anywhere.
// C/D layout: col = lane&15 (p), row = (lane>>4)*4 + reg (o) [HW-verified].
// ---------------------------------------------------------------------------
__global__ __launch_bounds__(256) void qkv_kernel(
    const float* __restrict__ x, const float* __restrict__ y,
    const unsigned* __restrict__ wpack, const float* __restrict__ wbias,
    uint4* __restrict__ q_pm, uint4* __restrict__ k_pm, uint4* __restrict__ v_pm)
{
    const int t   = threadIdx.x;
    const int blk = blockIdx.x;
    const int b   = blk & 7;
    const int p0  = (blk >> 3) << 6;    // 64-position tile base

    const int wv = t >> 6, ln = t & 63, lg = ln >> 4, li = ln & 15;
    const int pcol = p0 + wv * 16 + li;

    const float* xb = x + (size_t)b * CDIM * HW;
    const float* yb = y + (size_t)b * CDIM * HW;

    f32x4 acc[5];
    #pragma unroll
    for (int mt = 0; mt < 5; mt++) acc[mt] = (f32x4){0.f, 0.f, 0.f, 0.f};

    #pragma unroll
    for (int pair = 0; pair < 2; pair++) {
        const int chb = pair * 32 + lg * 8;          // channel base (k-slice)
        const float* xp = xb + (size_t)chb * HW + pcol;
        const float* yp = yb + (size_t)chb * HW + pcol;
        float fx[8], fy[8];
        #pragma unroll
        for (int e = 0; e < 8; e++) {
            fx[e] = xp[(size_t)e * HW];
            fy[e] = yp[(size_t)e * HW];
        }
        uint4 ux, uy;
        ux.x = pk_bf16(fx[0], fx[1]); ux.y = pk_bf16(fx[2], fx[3]);
        ux.z = pk_bf16(fx[4], fx[5]); ux.w = pk_bf16(fx[6], fx[7]);
        uy.x = pk_bf16(fy[0], fy[1]); uy.y = pk_bf16(fy[2], fy[3]);
        uy.z = pk_bf16(fy[4], fy[5]); uy.w = pk_bf16(fy[6], fy[7]);
        bf16x8 bx = *(bf16x8*)&ux;
        bf16x8 by = *(bf16x8*)&uy;

        #pragma unroll
        for (int mt = 0; mt < 5; mt++) {
            const int row = mt * 16 + li;
            // uint index: row*64 + (k-slice base)/2 ; x half cols 0..63, y half +32
            bf16x8 ax = *(const bf16x8*)&wpack[row * 64 + (pair * 16 + lg * 4)];
            bf16x8 ay = *(const bf16x8*)&wpack[row * 64 + 32 + (pair * 16 + lg * 4)];
            acc[mt] = __builtin_amdgcn_mfma_f32_16x16x32_bf16(ax, bx, acc[mt], 0, 0, 0);
            acc[mt] = __builtin_amdgcn_mfma_f32_16x16x32_bf16(ay, by, acc[mt], 0, 0, 0);
        }
    }

    // ---- epilogue: +bias (float4 from wbias), pack, direct store ----
    const size_t gp = (size_t)b * HW + (size_t)pcol;
    #pragma unroll
    for (int mt = 0; mt < 5; mt++) {
        const int ob = mt * 16 + lg * 4;
        float4 bb = *(const float4*)&wbias[ob];
        uint2 w;
        w.x = pk_bf16(acc[mt][0] + bb.x, acc[mt][1] + bb.y);
        w.y = pk_bf16(acc[mt][2] + bb.z, acc[mt][3] + bb.w);
        ushort* dst;
        if (ob < 8)       dst = (ushort*)q_pm + gp * 8 + ob;
        else if (ob < 16) dst = (ushort*)k_pm + gp * 8 + (ob - 8);
        else              dst = (ushort*)v_pm + gp * 64 + (ob - 16);
        *(uint2*)dst = w;
    }
}

// ---------------------------------------------------------------------------
// Kernel 2 (column branch): one block per (b, c).  V/P in LDS XOR-swizzled
// -> 52 KB LDS -> 3 blocks/CU.  (round-11 exact)
// ---------------------------------------------------------------------------
__global__ __launch_bounds__(256, 3) void colattn_kernel(
    const uint4* __restrict__ q_pm, const uint4* __restrict__ k_pm,
    const uint4* __restrict__ v_pm,
    ushort* __restrict__ H_t, float* __restrict__ mH_g, float* __restrict__ sH_g)
{
    __shared__ ushort Q_lds[128 * 8];     // [i][ch]
    __shared__ ushort K_lds[128 * 8];     // [j][ch]
    __shared__ ushort V_lds[64 * 128];    // [ch][j], XOR-swizzled
    __shared__ ushort P_lds[128 * 128];   // [i][j], XOR-swizzled; reused for H

    const int blk = blockIdx.x;
    const int b  = blk & 7;
    const int cc = blk >> 3;
    const int t  = threadIdx.x;

    if (t < 128) {
        *(uint4*)&Q_lds[t * 8] = q_pm[(size_t)b * HW + (size_t)t * 128 + cc];
    } else {
        int j = t - 128;
        *(uint4*)&K_lds[j * 8] = k_pm[(size_t)b * HW + (size_t)j * 128 + cc];
    }
    {
        int j = t & 127, h = t >> 7;
        const uint4* vp = v_pm + ((size_t)b * HW + (size_t)j * 128 + cc) * 8 + 4 * h;
        #pragma unroll
        for (int qd = 0; qd < 4; qd++) {
            uint4 vu = vp[qd];
            int ch0 = 32 * h + 8 * qd;     // multiple of 8
            V_lds[(ch0 + 0) * 128 + (j ^ (0 << 3))] = (ushort)(vu.x & 0xffff);
            V_lds[(ch0 + 1) * 128 + (j ^ (1 << 3))] = (ushort)(vu.x >> 16);
            V_lds[(ch0 + 2) * 128 + (j ^ (2 << 3))] = (ushort)(vu.y & 0xffff);
            V_lds[(ch0 + 3) * 128 + (j ^ (3 << 3))] = (ushort)(vu.y >> 16);
            V_lds[(ch0 + 4) * 128 + (j ^ (4 << 3))] = (ushort)(vu.z & 0xffff);
            V_lds[(ch0 + 5) * 128 + (j ^ (5 << 3))] = (ushort)(vu.z >> 16);
            V_lds[(ch0 + 6) * 128 + (j ^ (6 << 3))] = (ushort)(vu.w & 0xffff);
            V_lds[(ch0 + 7) * 128 + (j ^ (7 << 3))] = (ushort)(vu.w >> 16);
        }
    }
    __syncthreads();

    const int wv = t >> 6, ln = t & 63, lg = ln >> 4, li = ln & 15;
    const bf16x8 zf = {0, 0, 0, 0, 0, 0, 0, 0};

    // ---- QK^T ----
    bf16x8 afr[8], bfr[2];
    #pragma unroll
    for (int jt = 0; jt < 8; jt++)
        afr[jt] = (lg == 0) ? *(const bf16x8*)&K_lds[(jt * 16 + li) * 8] : zf;
    #pragma unroll
    for (int it2 = 0; it2 < 2; it2++)
        bfr[it2] = (lg == 0) ? *(const bf16x8*)&Q_lds[((2 * wv + it2) * 16 + li) * 8] : zf;

    f32x4 dfr[2][8];
    #pragma unroll
    for (int a = 0; a < 2; a++)
        #pragma unroll
        for (int jt = 0; jt < 8; jt++) dfr[a][jt] = (f32x4){0.f, 0.f, 0.f, 0.f};

    #pragma unroll
    for (int it2 = 0; it2 < 2; it2++)
        #pragma unroll
        for (int jt = 0; jt < 8; jt++)
            dfr[it2][jt] = __builtin_amdgcn_mfma_f32_16x16x32_bf16(
                afr[jt], bfr[it2], dfr[it2][jt], 0, 0, 0);

    // ---- softmax (unnormalized, diag masked) ----
    #pragma unroll
    for (int it2 = 0; it2 < 2; it2++) {
        const int i = (2 * wv + it2) * 16 + li;
        float m = -1e30f;
        #pragma unroll
        for (int jt = 0; jt < 8; jt++)
            #pragma unroll
            for (int rr = 0; rr < 4; rr++) {
                int j = jt * 16 + lg * 4 + rr;
                float e = dfr[it2][jt][rr];
                if (j == i) e = -1e30f;
                dfr[it2][jt][rr] = e;
                m = fmaxf(m, e);
            }
        m = fmaxf(m, __shfl_xor(m, 16));
        m = fmaxf(m, __shfl_xor(m, 32));
        float s = 0.f;
        #pragma unroll
        for (int jt = 0; jt < 8; jt++)
            #pragma unroll
            for (int rr = 0; rr < 4; rr++) {
                float p = __expf(dfr[it2][jt][rr] - m);
                dfr[it2][jt][rr] = p;
                s += p;
            }
        s += __shfl_xor(s, 16);
        s += __shfl_xor(s, 32);
        const int swz = (i & 7) << 3;
        #pragma unroll
        for (int jt = 0; jt < 8; jt++) {
            uint2 w;
            w.x = pk_bf16(dfr[it2][jt][0], dfr[it2][jt][1]);
            w.y = pk_bf16(dfr[it2][jt][2], dfr[it2][jt][3]);
            *(uint2*)&P_lds[i * 128 + ((jt * 16 + lg * 4) ^ swz)] = w;
        }
        if (lg == 0) {
            mH_g[((size_t)b * 128 + cc) * 128 + i] = m;
            sH_g[((size_t)b * 128 + cc) * 128 + i] = s;
        }
    }
    __syncthreads();

    // ---- PV ----
    f32x4 ofr[8];
    #pragma unroll
    for (int itl = 0; itl < 8; itl++) ofr[itl] = (f32x4){0.f, 0.f, 0.f, 0.f};

    const int vswz = (li & 7) << 3;
    #pragma unroll
    for (int ks = 0; ks < 4; ks++) {
        const int jb = ks * 32 + lg * 8;
        bf16x8 av = *(const bf16x8*)&V_lds[(wv * 16 + li) * 128 + (jb ^ vswz)];
        #pragma unroll
        for (int itl = 0; itl < 8; itl++) {
            bf16x8 bp = *(const bf16x8*)&P_lds[(itl * 16 + li) * 128 + (jb ^ vswz)];
            ofr[itl] = __builtin_amdgcn_mfma_f32_16x16x32_bf16(av, bp, ofr[itl], 0, 0, 0);
        }
    }
    __syncthreads();   // P_lds dead; reuse as H transpose buffer [128][72]

    #pragma unroll
    for (int itl = 0; itl < 8; itl++) {
        const int i = itl * 16 + li;
        uint2 w;
        w.x = pk_bf16(ofr[itl][0], ofr[itl][1]);
        w.y = pk_bf16(ofr[itl][2], ofr[itl][3]);
        *(uint2*)&P_lds[i * 72 + wv * 16 + lg * 4] = w;
    }
    __syncthreads();

    #pragma unroll
    for (int i2 = 0; i2 < 4; i2++) {
        const int f = t + i2 * 256;          // 128 i x 8 chunks
        const int i = f >> 3, cb = (f & 7) * 8;
        *(uint4*)&H_t[(((size_t)b * 128 + i) * 128 + cc) * 64 + cb] =
            *(const uint4*)&P_lds[i * 72 + cb];
    }
}

// ---------------------------------------------------------------------------
// Kernel 3 (row branch + merge): one block per (b, r).  (round-11 exact)
// ---------------------------------------------------------------------------
__global__ __launch_bounds__(256, 3) void rowattn_kernel(
    const uint4* __restrict__ q_pm, const uint4* __restrict__ k_pm,
    const uint4* __restrict__ v_pm,
    const ushort* __restrict__ H_t, const float* __restrict__ mH_g,
    const float* __restrict__ sH_g,
    const float* __restrict__ x, const float* __restrict__ y,
    const float* __restrict__ gptr, float* __restrict__ out)
{
    __shared__ ushort Q_lds[128 * 8];     // [i][ch]  (i = column index)
    __shared__ ushort K_lds[128 * 8];     // [j][ch]
    __shared__ ushort V_lds[64 * 128];    // [ch][j], XOR-swizzled
    __shared__ ushort P_lds[128 * 128];   // [i][j], XOR-swizzled
    __shared__ float mW_s[128], sW_s[128];

    const int blk = blockIdx.x;
    const int b = blk & 7;
    const int r = blk >> 3;
    const int t = threadIdx.x;

    if (t < 128) {
        *(uint4*)&Q_lds[t * 8] = q_pm[(size_t)b * HW + (size_t)r * 128 + t];
    } else {
        int j = t - 128;
        *(uint4*)&K_lds[j * 8] = k_pm[(size_t)b * HW + (size_t)r * 128 + j];
    }
    {
        int j = t & 127, h = t >> 7;
        const uint4* vp = v_pm + ((size_t)b * HW + (size_t)r * 128 + j) * 8 + 4 * h;
        #pragma unroll
        for (int qd = 0; qd < 4; qd++) {
            uint4 vu = vp[qd];
            int ch0 = 32 * h + 8 * qd;
            V_lds[(ch0 + 0) * 128 + (j ^ (0 << 3))] = (ushort)(vu.x & 0xffff);
            V_lds[(ch0 + 1) * 128 + (j ^ (1 << 3))] = (ushort)(vu.x >> 16);
            V_lds[(ch0 + 2) * 128 + (j ^ (2 << 3))] = (ushort)(vu.y & 0xffff);
            V_lds[(ch0 + 3) * 128 + (j ^ (3 << 3))] = (ushort)(vu.y >> 16);
            V_lds[(ch0 + 4) * 128 + (j ^ (4 << 3))] = (ushort)(vu.z & 0xffff);
            V_lds[(ch0 + 5) * 128 + (j ^ (5 << 3))] = (ushort)(vu.z >> 16);
            V_lds[(ch0 + 6) * 128 + (j ^ (6 << 3))] = (ushort)(vu.w & 0xffff);
            V_lds[(ch0 + 7) * 128 + (j ^ (7 << 3))] = (ushort)(vu.w >> 16);
        }
    }
    __syncthreads();

    const int wv = t >> 6, ln = t & 63, lg = ln >> 4, li = ln & 15;
    const bf16x8 zf = {0, 0, 0, 0, 0, 0, 0, 0};

    bf16x8 afr[8], bfr[2];
    #pragma unroll
    for (int jt = 0; jt < 8; jt++)
        afr[jt] = (lg == 0) ? *(const bf16x8*)&K_lds[(jt * 16 + li) * 8] : zf;
    #pragma unroll
    for (int it2 = 0; it2 < 2; it2++)
        bfr[it2] = (lg == 0) ? *(const bf16x8*)&Q_lds[((2 * wv + it2) * 16 + li) * 8] : zf;

    f32x4 dfr[2][8];
    #pragma unroll
    for (int a = 0; a < 2; a++)
        #pragma unroll
        for (int jt = 0; jt < 8; jt++) dfr[a][jt] = (f32x4){0.f, 0.f, 0.f, 0.f};

    #pragma unroll
    for (int it2 = 0; it2 < 2; it2++)
        #pragma unroll
        for (int jt = 0; jt < 8; jt++)
            dfr[it2][jt] = __builtin_amdgcn_mfma_f32_16x16x32_bf16(
                afr[jt], bfr[it2], dfr[it2][jt], 0, 0, 0);

    #pragma unroll
    for (int it2 = 0; it2 < 2; it2++) {
        const int i = (2 * wv + it2) * 16 + li;
        float m = -1e30f;
        #pragma unroll
        for (int jt = 0; jt < 8; jt++)
            #pragma unroll
            for (int rr = 0; rr < 4; rr++)
                m = fmaxf(m, dfr[it2][jt][rr]);
        m = fmaxf(m, __shfl_xor(m, 16));
        m = fmaxf(m, __shfl_xor(m, 32));
        float s = 0.f;
        #pragma unroll
        for (int jt = 0; jt < 8; jt++)
            #pragma unroll
            for (int rr = 0; rr < 4; rr++) {
                float p = __expf(dfr[it2][jt][rr] - m);
                dfr[it2][jt][rr] = p;
                s += p;
            }
        s += __shfl_xor(s, 16);
        s += __shfl_xor(s, 32);
        const int swz = (i & 7) << 3;
        #pragma unroll
        for (int jt = 0; jt < 8; jt++) {
            uint2 w;
            w.x = pk_bf16(dfr[it2][jt][0], dfr[it2][jt][1]);
            w.y = pk_bf16(dfr[it2][jt][2], dfr[it2][jt][3]);
            *(uint2*)&P_lds[i * 128 + ((jt * 16 + lg * 4) ^ swz)] = w;
        }
        if (lg == 0) {
            mW_s[i] = m;
            sW_s[i] = s;
        }
    }
    __syncthreads();

    f32x4 ofr[8];
    #pragma unroll
    for (int itl = 0; itl < 8; itl++) ofr[itl] = (f32x4){0.f, 0.f, 0.f, 0.f};

    const int vswz = (li & 7) << 3;
    #pragma unroll
    for (int ks = 0; ks < 4; ks++) {
        const int jb = ks * 32 + lg * 8;
        bf16x8 av = *(const bf16x8*)&V_lds[(wv * 16 + li) * 128 + (jb ^ vswz)];
        #pragma unroll
        for (int itl = 0; itl < 8; itl++) {
            bf16x8 bp = *(const bf16x8*)&P_lds[(itl * 16 + li) * 128 + (jb ^ vswz)];
            ofr[itl] = __builtin_amdgcn_mfma_f32_16x16x32_bf16(av, bp, ofr[itl], 0, 0, 0);
        }
    }

    const float gamma = gptr[0];
    #pragma unroll
    for (int itl = 0; itl < 8; itl++) {
        const int i = itl * 16 + li;     // column index of this position
        float mWv = mW_s[i], sWv = sW_s[i];
        float mHv = mH_g[((size_t)b * 128 + i) * 128 + r];
        float sHv = sH_g[((size_t)b * 128 + i) * 128 + r];
        float m  = fmaxf(mHv, mWv);
        float wH = __expf(mHv - m);
        float wW = __expf(mWv - m);
        float invg = gamma / (sHv * wH + sWv * wW);

        uint2 hw = *(const uint2*)&H_t[(((size_t)b * 128 + r) * 128 + i) * 64 + wv * 16 + lg * 4];
        float h[4];
        cvt2(hw.x, h[0], h[1]);
        cvt2(hw.y, h[2], h[3]);

        #pragma unroll
        for (int rr = 0; rr < 4; rr++) {
            const int ch = wv * 16 + lg * 4 + rr;
            size_t o = (((size_t)b * 64 + ch) * 128 + r) * 128 + i;
            out[o] = (h[rr] * wH + ofr[itl][rr] * wW) * invg + x[o] + y[o];
        }
    }
}

// ---------------------------------------------------------------------------
extern "C" void kernel_launch(void* const* d_in, const int* in_sizes, int n_in,
                              void* d_out, int out_size, void* d_ws, size_t ws_size,
                              hipStream_t stream)
{
    const float* x     = (const float*)d_in[0];
    const float* y     = (const float*)d_in[1];
    const float* Wq    = (const float*)d_in[2];
    const float* bq    = (const float*)d_in[3];
    const float* Wk    = (const float*)d_in[4];
    const float* bk    = (const float*)d_in[5];
    const float* Wv    = (const float*)d_in[6];
    const float* bv    = (const float*)d_in[7];
    const float* gamma = (const float*)d_in[8];
    float* out = (float*)d_out;

    // Workspace: q 2MB | k 2MB | v 16MB | H_t 16MB | mH .5MB | sH .5MB | wpack+bias
    uint4*    q_pm  = (uint4*)d_ws;                        // 131072 uint4
    uint4*    k_pm  = q_pm + (size_t)BDIM * HW;            // 131072 uint4
    uint4*    v_pm  = k_pm + (size_t)BDIM * HW;            // 1048576 uint4
    ushort*   H_t   = (ushort*)(v_pm + (size_t)BDIM * HW * 8);   // 8388608 us
    float*    mH    = (float*)(H_t + (size_t)BDIM * HW * 64);
    float*    sH    = mH + (size_t)BDIM * HW;
    unsigned* wpack = (unsigned*)(sH + (size_t)BDIM * HW);       // 5120 uint
    float*    wbias = (float*)(wpack + 80 * 64);                 // 80 float

    prep_kernel<<<dim3(1), dim3(512), 0, stream>>>(
        Wq, bq, Wk, bk, Wv, bv, wpack, wbias);

    // 2048 blocks x 256 threads: (b = blk&7, 64-position tile), no LDS/barriers
    qkv_kernel<<<dim3(BDIM * HW / 64), dim3(256), 0, stream>>>(
        x, y, wpack, wbias, q_pm, k_pm, v_pm);

    colattn_kernel<<<dim3(BDIM * WDIM), dim3(256), 0, stream>>>(
        q_pm, k_pm, v_pm, H_t, mH, sH);

    rowattn_kernel<<<dim3(BDIM * HDIM), dim3(256), 0, stream>>>(
        q_pm, k_pm, v_pm, H_t, mH, sH, x, y, gamma, out);
}

// Round 17
// 63.067 us; speedup vs baseline: 1.2051x; 1.2051x over previous
//
#include <hip/hip_runtime.h>
#include <hip/hip_bf16.h>

// Problem constants: B=8, C=64, C8=8, H=128, W=128
#define BDIM 8
#define CDIM 64
#define C8DIM 8
#define HDIM 128
#define WDIM 128
#define HW (HDIM * WDIM)   // 16384

typedef short bf16x8 __attribute__((ext_vector_type(8)));
typedef float f32x4 __attribute__((ext_vector_type(4)));

// ---------------- bf16 helpers ----------------
__device__ inline unsigned pk_bf16(float a, float b) {
    unsigned ua = (unsigned)__bfloat16_as_ushort(__float2bfloat16(a));
    unsigned ub = (unsigned)__bfloat16_as_ushort(__float2bfloat16(b));
    return ua | (ub << 16);
}
__device__ inline void cvt2(unsigned u, float& lo, float& hi) {
    lo = __uint_as_float(u << 16);
    hi = __uint_as_float(u & 0xffff0000u);
}

// ---------------------------------------------------------------------------
// Kernel 1: fused QKV projection as MFMA GEMM (round-11 proven config).
// 1024 blocks x 512 threads (8 waves); wave owns one 16-position n-tile.
// ---------------------------------------------------------------------------
__global__ __launch_bounds__(512) void qkv_kernel(
    const float* __restrict__ x, const float* __restrict__ y,
    const float* __restrict__ Wq, const float* __restrict__ bq,
    const float* __restrict__ Wk, const float* __restrict__ bk,
    const float* __restrict__ Wv, const float* __restrict__ bv,
    uint4* __restrict__ q_pm, uint4* __restrict__ k_pm, uint4* __restrict__ v_pm)
{
    __shared__ ushort sW[80 * 128];   // [o][c] bf16, XOR-swizzled
    __shared__ float  sb[80];

    const int t = threadIdx.x;

    for (int i = t; i < 80 * 64; i += 512) {
        int o  = i >> 6;
        int cp = i & 63;
        int c  = cp * 2;
        float w0, w1;
        if (o < 8) {
            if (c < 64) { w0 = Wq[o * 64 + c]; w1 = Wq[o * 64 + c + 1]; }
            else        { w0 = 0.f; w1 = 0.f; }
        } else if (o < 16) {
            if (c >= 64) { w0 = Wk[(o - 8) * 64 + c - 64]; w1 = Wk[(o - 8) * 64 + c - 63]; }
            else         { w0 = 0.f; w1 = 0.f; }
        } else {
            w0 = Wv[(o - 16) * 128 + c];
            w1 = Wv[(o - 16) * 128 + c + 1];
        }
        ((unsigned*)sW)[o * 64 + (cp ^ ((o & 7) << 2))] = pk_bf16(w0, w1);
    }
    if (t < 80) {
        sb[t] = (t < 8) ? bq[t] : (t < 16) ? bk[t - 8] : bv[t - 16];
    }
    __syncthreads();

    const int blk = blockIdx.x;
    const int b   = blk & 7;
    const int p0  = (blk >> 3) << 7;

    const int wv = t >> 6, ln = t & 63, lg = ln >> 4, li = ln & 15;
    const int pcol = p0 + wv * 16 + li;

    const float* xb = x + (size_t)b * CDIM * HW;
    const float* yb = y + (size_t)b * CDIM * HW;

    f32x4 acc[5];
    #pragma unroll
    for (int mt = 0; mt < 5; mt++) acc[mt] = (f32x4){0.f, 0.f, 0.f, 0.f};

    #pragma unroll
    for (int pair = 0; pair < 2; pair++) {
        const int chb = pair * 32 + lg * 8;
        const float* xp = xb + (size_t)chb * HW + pcol;
        const float* yp = yb + (size_t)chb * HW + pcol;
        float fx[8], fy[8];
        #pragma unroll
        for (int e = 0; e < 8; e++) {
            fx[e] = xp[(size_t)e * HW];
            fy[e] = yp[(size_t)e * HW];
        }
        uint4 ux, uy;
        ux.x = pk_bf16(fx[0], fx[1]); ux.y = pk_bf16(fx[2], fx[3]);
        ux.z = pk_bf16(fx[4], fx[5]); ux.w = pk_bf16(fx[6], fx[7]);
        uy.x = pk_bf16(fy[0], fy[1]); uy.y = pk_bf16(fy[2], fy[3]);
        uy.z = pk_bf16(fy[4], fy[5]); uy.w = pk_bf16(fy[6], fy[7]);
        bf16x8 bx = *(bf16x8*)&ux;
        bf16x8 by = *(bf16x8*)&uy;

        #pragma unroll
        for (int mt = 0; mt < 5; mt++) {
            const int row = mt * 16 + li;
            const int sw  = ((li & 7) << 3);
            bf16x8 ax = *(const bf16x8*)&sW[row * 128 + ((pair * 32 + lg * 8) ^ sw)];
            bf16x8 ay = *(const bf16x8*)&sW[row * 128 + (((2 + pair) * 32 + lg * 8) ^ sw)];
            acc[mt] = __builtin_amdgcn_mfma_f32_16x16x32_bf16(ax, bx, acc[mt], 0, 0, 0);
            acc[mt] = __builtin_amdgcn_mfma_f32_16x16x32_bf16(ay, by, acc[mt], 0, 0, 0);
        }
    }

    const size_t gp = (size_t)b * HW + (size_t)pcol;
    #pragma unroll
    for (int mt = 0; mt < 5; mt++) {
        const int ob = mt * 16 + lg * 4;
        uint2 w;
        w.x = pk_bf16(acc[mt][0] + sb[ob + 0], acc[mt][1] + sb[ob + 1]);
        w.y = pk_bf16(acc[mt][2] + sb[ob + 2], acc[mt][3] + sb[ob + 3]);
        ushort* dst;
        if (ob < 8)       dst = (ushort*)q_pm + gp * 8 + ob;
        else if (ob < 16) dst = (ushort*)k_pm + gp * 8 + (ob - 8);
        else              dst = (ushort*)v_pm + gp * 64 + (ob - 16);
        *(uint2*)dst = w;
    }
}

// ---------------------------------------------------------------------------
// Kernel 2 (column branch): one block per (b, c).  V/P in LDS XOR-swizzled
// (ushort col ^= ((row&7)<<3)) -> 52 KB LDS -> 3 blocks/CU.
// ---------------------------------------------------------------------------
__global__ __launch_bounds__(256, 3) void colattn_kernel(
    const uint4* __restrict__ q_pm, const uint4* __restrict__ k_pm,
    const uint4* __restrict__ v_pm,
    ushort* __restrict__ H_t, float* __restrict__ mH_g, float* __restrict__ sH_g)
{
    __shared__ ushort Q_lds[128 * 8];     // [i][ch]
    __shared__ ushort K_lds[128 * 8];     // [j][ch]
    __shared__ ushort V_lds[64 * 128];    // [ch][j], XOR-swizzled
    __shared__ ushort P_lds[128 * 128];   // [i][j], XOR-swizzled; reused for H

    const int blk = blockIdx.x;
    const int b  = blk & 7;
    const int cc = blk >> 3;
    const int t  = threadIdx.x;

    if (t < 128) {
        *(uint4*)&Q_lds[t * 8] = q_pm[(size_t)b * HW + (size_t)t * 128 + cc];
    } else {
        int j = t - 128;
        *(uint4*)&K_lds[j * 8] = k_pm[(size_t)b * HW + (size_t)j * 128 + cc];
    }
    {
        int j = t & 127, h = t >> 7;
        const uint4* vp = v_pm + ((size_t)b * HW + (size_t)j * 128 + cc) * 8 + 4 * h;
        #pragma unroll
        for (int qd = 0; qd < 4; qd++) {
            uint4 vu = vp[qd];
            int ch0 = 32 * h + 8 * qd;
            V_lds[(ch0 + 0) * 128 + (j ^ (0 << 3))] = (ushort)(vu.x & 0xffff);
            V_lds[(ch0 + 1) * 128 + (j ^ (1 << 3))] = (ushort)(vu.x >> 16);
            V_lds[(ch0 + 2) * 128 + (j ^ (2 << 3))] = (ushort)(vu.y & 0xffff);
            V_lds[(ch0 + 3) * 128 + (j ^ (3 << 3))] = (ushort)(vu.y >> 16);
            V_lds[(ch0 + 4) * 128 + (j ^ (4 << 3))] = (ushort)(vu.z & 0xffff);
            V_lds[(ch0 + 5) * 128 + (j ^ (5 << 3))] = (ushort)(vu.z >> 16);
            V_lds[(ch0 + 6) * 128 + (j ^ (6 << 3))] = (ushort)(vu.w & 0xffff);
            V_lds[(ch0 + 7) * 128 + (j ^ (7 << 3))] = (ushort)(vu.w >> 16);
        }
    }
    __syncthreads();

    const int wv = t >> 6, ln = t & 63, lg = ln >> 4, li = ln & 15;
    const bf16x8 zf = {0, 0, 0, 0, 0, 0, 0, 0};

    // ---- QK^T ----
    bf16x8 afr[8], bfr[2];
    #pragma unroll
    for (int jt = 0; jt < 8; jt++)
        afr[jt] = (lg == 0) ? *(const bf16x8*)&K_lds[(jt * 16 + li) * 8] : zf;
    #pragma unroll
    for (int it2 = 0; it2 < 2; it2++)
        bfr[it2] = (lg == 0) ? *(const bf16x8*)&Q_lds[((2 * wv + it2) * 16 + li) * 8] : zf;

    f32x4 dfr[2][8];
    #pragma unroll
    for (int a = 0; a < 2; a++)
        #pragma unroll
        for (int jt = 0; jt < 8; jt++) dfr[a][jt] = (f32x4){0.f, 0.f, 0.f, 0.f};

    #pragma unroll
    for (int it2 = 0; it2 < 2; it2++)
        #pragma unroll
        for (int jt = 0; jt < 8; jt++)
            dfr[it2][jt] = __builtin_amdgcn_mfma_f32_16x16x32_bf16(
                afr[jt], bfr[it2], dfr[it2][jt], 0, 0, 0);

    // ---- softmax (unnormalized, diag masked) ----
    #pragma unroll
    for (int it2 = 0; it2 < 2; it2++) {
        const int i = (2 * wv + it2) * 16 + li;
        float m = -1e30f;
        #pragma unroll
        for (int jt = 0; jt < 8; jt++)
            #pragma unroll
            for (int rr = 0; rr < 4; rr++) {
                int j = jt * 16 + lg * 4 + rr;
                float e = dfr[it2][jt][rr];
                if (j == i) e = -1e30f;
                dfr[it2][jt][rr] = e;
                m = fmaxf(m, e);
            }
        m = fmaxf(m, __shfl_xor(m, 16));
        m = fmaxf(m, __shfl_xor(m, 32));
        float s = 0.f;
        #pragma unroll
        for (int jt = 0; jt < 8; jt++)
            #pragma unroll
            for (int rr = 0; rr < 4; rr++) {
                float p = __expf(dfr[it2][jt][rr] - m);
                dfr[it2][jt][rr] = p;
                s += p;
            }
        s += __shfl_xor(s, 16);
        s += __shfl_xor(s, 32);
        const int swz = (i & 7) << 3;
        #pragma unroll
        for (int jt = 0; jt < 8; jt++) {
            uint2 w;
            w.x = pk_bf16(dfr[it2][jt][0], dfr[it2][jt][1]);
            w.y = pk_bf16(dfr[it2][jt][2], dfr[it2][jt][3]);
            *(uint2*)&P_lds[i * 128 + ((jt * 16 + lg * 4) ^ swz)] = w;
        }
        if (lg == 0) {
            mH_g[((size_t)b * 128 + cc) * 128 + i] = m;
            sH_g[((size_t)b * 128 + cc) * 128 + i] = s;
        }
    }
    __syncthreads();

    // ---- PV ----
    f32x4 ofr[8];
    #pragma unroll
    for (int itl = 0; itl < 8; itl++) ofr[itl] = (f32x4){0.f, 0.f, 0.f, 0.f};

    const int vswz = (li & 7) << 3;
    #pragma unroll
    for (int ks = 0; ks < 4; ks++) {
        const int jb = ks * 32 + lg * 8;
        bf16x8 av = *(const bf16x8*)&V_lds[(wv * 16 + li) * 128 + (jb ^ vswz)];
        #pragma unroll
        for (int itl = 0; itl < 8; itl++) {
            bf16x8 bp = *(const bf16x8*)&P_lds[(itl * 16 + li) * 128 + (jb ^ vswz)];
            ofr[itl] = __builtin_amdgcn_mfma_f32_16x16x32_bf16(av, bp, ofr[itl], 0, 0, 0);
        }
    }
    __syncthreads();   // P_lds dead; reuse as H transpose buffer [128][72]

    #pragma unroll
    for (int itl = 0; itl < 8; itl++) {
        const int i = itl * 16 + li;
        uint2 w;
        w.x = pk_bf16(ofr[itl][0], ofr[itl][1]);
        w.y = pk_bf16(ofr[itl][2], ofr[itl][3]);
        *(uint2*)&P_lds[i * 72 + wv * 16 + lg * 4] = w;
    }
    __syncthreads();

    #pragma unroll
    for (int i2 = 0; i2 < 4; i2++) {
        const int f = t + i2 * 256;          // 128 i x 8 chunks
        const int i = f >> 3, cb = (f & 7) * 8;
        *(uint4*)&H_t[(((size_t)b * 128 + i) * 128 + cc) * 64 + cb] =
            *(const uint4*)&P_lds[i * 72 + cb];
    }
}

// ---------------------------------------------------------------------------
// Kernel 3 (row branch + merge): one block per (b, r).
// ---------------------------------------------------------------------------
__global__ __launch_bounds__(256, 3) void rowattn_kernel(
    const uint4* __restrict__ q_pm, const uint4* __restrict__ k_pm,
    const uint4* __restrict__ v_pm,
    const ushort* __restrict__ H_t, const float* __restrict__ mH_g,
    const float* __restrict__ sH_g,
    const float* __restrict__ x, const float* __restrict__ y,
    const float* __restrict__ gptr, float* __restrict__ out)
{
    __shared__ ushort Q_lds[128 * 8];     // [i][ch]  (i = column index)
    __shared__ ushort K_lds[128 * 8];     // [j][ch]
    __shared__ ushort V_lds[64 * 128];    // [ch][j], XOR-swizzled
    __shared__ ushort P_lds[128 * 128];   // [i][j], XOR-swizzled
    __shared__ float mW_s[128], sW_s[128];

    const int blk = blockIdx.x;
    const int b = blk & 7;
    const int r = blk >> 3;
    const int t = threadIdx.x;

    if (t < 128) {
        *(uint4*)&Q_lds[t * 8] = q_pm[(size_t)b * HW + (size_t)r * 128 + t];
    } else {
        int j = t - 128;
        *(uint4*)&K_lds[j * 8] = k_pm[(size_t)b * HW + (size_t)r * 128 + j];
    }
    {
        int j = t & 127, h = t >> 7;
        const uint4* vp = v_pm + ((size_t)b * HW + (size_t)r * 128 + j) * 8 + 4 * h;
        #pragma unroll
        for (int qd = 0; qd < 4; qd++) {
            uint4 vu = vp[qd];
            int ch0 = 32 * h + 8 * qd;
            V_lds[(ch0 + 0) * 128 + (j ^ (0 << 3))] = (ushort)(vu.x & 0xffff);
            V_lds[(ch0 + 1) * 128 + (j ^ (1 << 3))] = (ushort)(vu.x >> 16);
            V_lds[(ch0 + 2) * 128 + (j ^ (2 << 3))] = (ushort)(vu.y & 0xffff);
            V_lds[(ch0 + 3) * 128 + (j ^ (3 << 3))] = (ushort)(vu.y >> 16);
            V_lds[(ch0 + 4) * 128 + (j ^ (4 << 3))] = (ushort)(vu.z & 0xffff);
            V_lds[(ch0 + 5) * 128 + (j ^ (5 << 3))] = (ushort)(vu.z >> 16);
            V_lds[(ch0 + 6) * 128 + (j ^ (6 << 3))] = (ushort)(vu.w & 0xffff);
            V_lds[(ch0 + 7) * 128 + (j ^ (7 << 3))] = (ushort)(vu.w >> 16);
        }
    }
    __syncthreads();

    const int wv = t >> 6, ln = t & 63, lg = ln >> 4, li = ln & 15;
    const bf16x8 zf = {0, 0, 0, 0, 0, 0, 0, 0};

    bf16x8 afr[8], bfr[2];
    #pragma unroll
    for (int jt = 0; jt < 8; jt++)
        afr[jt] = (lg == 0) ? *(const bf16x8*)&K_lds[(jt * 16 + li) * 8] : zf;
    #pragma unroll
    for (int it2 = 0; it2 < 2; it2++)
        bfr[it2] = (lg == 0) ? *(const bf16x8*)&Q_lds[((2 * wv + it2) * 16 + li) * 8] : zf;

    f32x4 dfr[2][8];
    #pragma unroll
    for (int a = 0; a < 2; a++)
        #pragma unroll
        for (int jt = 0; jt < 8; jt++) dfr[a][jt] = (f32x4){0.f, 0.f, 0.f, 0.f};

    #pragma unroll
    for (int it2 = 0; it2 < 2; it2++)
        #pragma unroll
        for (int jt = 0; jt < 8; jt++)
            dfr[it2][jt] = __builtin_amdgcn_mfma_f32_16x16x32_bf16(
                afr[jt], bfr[it2], dfr[it2][jt], 0, 0, 0);

    #pragma unroll
    for (int it2 = 0; it2 < 2; it2++) {
        const int i = (2 * wv + it2) * 16 + li;
        float m = -1e30f;
        #pragma unroll
        for (int jt = 0; jt < 8; jt++)
            #pragma unroll
            for (int rr = 0; rr < 4; rr++)
                m = fmaxf(m, dfr[it2][jt][rr]);
        m = fmaxf(m, __shfl_xor(m, 16));
        m = fmaxf(m, __shfl_xor(m, 32));
        float s = 0.f;
        #pragma unroll
        for (int jt = 0; jt < 8; jt++)
            #pragma unroll
            for (int rr = 0; rr < 4; rr++) {
                float p = __expf(dfr[it2][jt][rr] - m);
                dfr[it2][jt][rr] = p;
                s += p;
            }
        s += __shfl_xor(s, 16);
        s += __shfl_xor(s, 32);
        const int swz = (i & 7) << 3;
        #pragma unroll
        for (int jt = 0; jt < 8; jt++) {
            uint2 w;
            w.x = pk_bf16(dfr[it2][jt][0], dfr[it2][jt][1]);
            w.y = pk_bf16(dfr[it2][jt][2], dfr[it2][jt][3]);
            *(uint2*)&P_lds[i * 128 + ((jt * 16 + lg * 4) ^ swz)] = w;
        }
        if (lg == 0) {
            mW_s[i] = m;
            sW_s[i] = s;
        }
    }
    __syncthreads();

    f32x4 ofr[8];
    #pragma unroll
    for (int itl = 0; itl < 8; itl++) ofr[itl] = (f32x4){0.f, 0.f, 0.f, 0.f};

    const int vswz = (li & 7) << 3;
    #pragma unroll
    for (int ks = 0; ks < 4; ks++) {
        const int jb = ks * 32 + lg * 8;
        bf16x8 av = *(const bf16x8*)&V_lds[(wv * 16 + li) * 128 + (jb ^ vswz)];
        #pragma unroll
        for (int itl = 0; itl < 8; itl++) {
            bf16x8 bp = *(const bf16x8*)&P_lds[(itl * 16 + li) * 128 + (jb ^ vswz)];
            ofr[itl] = __builtin_amdgcn_mfma_f32_16x16x32_bf16(av, bp, ofr[itl], 0, 0, 0);
        }
    }

    const float gamma = gptr[0];
    #pragma unroll
    for (int itl = 0; itl < 8; itl++) {
        const int i = itl * 16 + li;     // column index of this position
        float mWv = mW_s[i], sWv = sW_s[i];
        float mHv = mH_g[((size_t)b * 128 + i) * 128 + r];
        float sHv = sH_g[((size_t)b * 128 + i) * 128 + r];
        float m  = fmaxf(mHv, mWv);
        float wH = __expf(mHv - m);
        float wW = __expf(mWv - m);
        float invg = gamma / (sHv * wH + sWv * wW);

        uint2 hw = *(const uint2*)&H_t[(((size_t)b * 128 + r) * 128 + i) * 64 + wv * 16 + lg * 4];
        float h[4];
        cvt2(hw.x, h[0], h[1]);
        cvt2(hw.y, h[2], h[3]);

        #pragma unroll
        for (int rr = 0; rr < 4; rr++) {
            const int ch = wv * 16 + lg * 4 + rr;
            size_t o = (((size_t)b * 64 + ch) * 128 + r) * 128 + i;
            out[o] = (h[rr] * wH + ofr[itl][rr] * wW) * invg + x[o] + y[o];
        }
    }
}

// ---------------------------------------------------------------------------
extern "C" void kernel_launch(void* const* d_in, const int* in_sizes, int n_in,
                              void* d_out, int out_size, void* d_ws, size_t ws_size,
                              hipStream_t stream)
{
    const float* x     = (const float*)d_in[0];
    const float* y     = (const float*)d_in[1];
    const float* Wq    = (const float*)d_in[2];
    const float* bq    = (const float*)d_in[3];
    const float* Wk    = (const float*)d_in[4];
    const float* bk    = (const float*)d_in[5];
    const float* Wv    = (const float*)d_in[6];
    const float* bv    = (const float*)d_in[7];
    const float* gamma = (const float*)d_in[8];
    float* out = (float*)d_out;

    // Workspace: q 2MB | k 2MB | v 16MB | H_t 16MB | mH .5MB | sH .5MB
    uint4*  q_pm = (uint4*)d_ws;                        // 131072 uint4
    uint4*  k_pm = q_pm + (size_t)BDIM * HW;            // 131072 uint4
    uint4*  v_pm = k_pm + (size_t)BDIM * HW;            // 1048576 uint4
    ushort* H_t  = (ushort*)(v_pm + (size_t)BDIM * HW * 8);      // 8388608 us
    float*  mH   = (float*)(H_t + (size_t)BDIM * HW * 64);
    float*  sH   = mH + (size_t)BDIM * HW;

    qkv_kernel<<<dim3(BDIM * HW / 128), dim3(512), 0, stream>>>(
        x, y, Wq, bq, Wk, bk, Wv, bv, q_pm, k_pm, v_pm);

    colattn_kernel<<<dim3(BDIM * WDIM), dim3(256), 0, stream>>>(
        q_pm, k_pm, v_pm, H_t, mH, sH);

    rowattn_kernel<<<dim3(BDIM * HDIM), dim3(256), 0, stream>>>(
        q_pm, k_pm, v_pm, H_t, mH, sH, x, y, gamma, out);
}